// Round 1
// baseline (148.686 us; speedup 1.0000x reference)
//
#include <hip/hip_runtime.h>
#include <math.h>

#define N 4096
#define D 128
#define TILE 128
#define BK 64
#define NT (N / TILE)              // 32 tile rows
#define NBLK (NT * (NT + 1) / 2)   // 528 lower-triangle tile pairs

// Kernel 1: s[i] = sqrt(1 + ||o_i||^2); also zeroes the loss accumulator.
// One wave (64 threads) per row, float2 per lane.
__global__ void snorm_kernel(const float* __restrict__ O,
                             float* __restrict__ s,
                             float* __restrict__ loss) {
    const int row  = blockIdx.x;
    const int lane = threadIdx.x;          // 0..63
    const float2 v = *(const float2*)(O + (size_t)row * D + 2 * lane);
    float acc = v.x * v.x + v.y * v.y;
    #pragma unroll
    for (int off = 32; off > 0; off >>= 1)
        acc += __shfl_down(acc, off, 64);
    if (lane == 0) {
        s[row] = sqrtf(1.0f + acc);
        if (row == 0) loss[0] = 0.0f;      // runs before kernel 2 (stream order)
    }
}

// Kernel 2: one block per lower-triangle 128x128 tile pair (bi >= bj).
// LDS tiles stored transposed [k][row] so fragment reads are ds_read_b128
// (stride 128 floats -> 16B aligned, 2-way bank aliasing = free).
__global__ __launch_bounds__(256, 2)
void tile_loss_kernel(const float* __restrict__ O,
                      const float* __restrict__ s,
                      const float* __restrict__ tgt,
                      float* __restrict__ loss) {
    __shared__ float As[BK][TILE];   // [k][row]  32 KB
    __shared__ float Bs[BK][TILE];   // [k][col]  32 KB
    __shared__ float wsum[4];

    // Linear tile id -> (bi, bj), bj <= bi, t = bi*(bi+1)/2 + bj
    const int t = blockIdx.x;
    int bi = (int)((sqrtf(8.0f * (float)t + 1.0f) - 1.0f) * 0.5f);
    while ((bi + 1) * (bi + 2) / 2 <= t) bi++;
    while (bi * (bi + 1) / 2 > t) bi--;
    const int bj = t - bi * (bi + 1) / 2;

    const int tid  = threadIdx.x;
    const int wave = tid >> 6;             // 0..3
    const int lane = tid & 63;
    const int txw  = lane & 7;             // 0..7  (cols within wave)
    const int tyw  = lane >> 3;            // 0..7  (rows within wave)
    const int wrow = (wave >> 1) * 64;     // wave quadrant in 128x128 tile
    const int wcol = (wave & 1) * 64;

    const int rowbase = bi * TILE;
    const int colbase = bj * TILE;

    float acc[8][8];
    #pragma unroll
    for (int r = 0; r < 8; r++)
        #pragma unroll
        for (int c = 0; c < 8; c++) acc[r][c] = 0.0f;

    // Staging lane map: lane covers 64 rows for fixed k-quad (wave-uniform kq)
    const int lrow = tid & 63;
    const int kq0  = tid >> 6;             // 0..3, uniform per wave

    for (int k0 = 0; k0 < D; k0 += BK) {
        #pragma unroll
        for (int kk = 0; kk < 4; kk++) {
            const int kq = kq0 + kk * 4;   // float4 index within k-chunk (0..15)
            #pragma unroll
            for (int rg = 0; rg < 2; rg++) {
                const int row = lrow + rg * 64;
                const float4 va = *(const float4*)(O + (size_t)(rowbase + row) * D + k0 + kq * 4);
                As[kq * 4 + 0][row] = va.x;
                As[kq * 4 + 1][row] = va.y;
                As[kq * 4 + 2][row] = va.z;
                As[kq * 4 + 3][row] = va.w;
                const float4 vb = *(const float4*)(O + (size_t)(colbase + row) * D + k0 + kq * 4);
                Bs[kq * 4 + 0][row] = vb.x;
                Bs[kq * 4 + 1][row] = vb.y;
                Bs[kq * 4 + 2][row] = vb.z;
                Bs[kq * 4 + 3][row] = vb.w;
            }
        }
        __syncthreads();

        #pragma unroll 8
        for (int k = 0; k < BK; k++) {
            float a[8], b[8];
            *(float4*)&a[0] = *(const float4*)&As[k][wrow + tyw * 8];
            *(float4*)&a[4] = *(const float4*)&As[k][wrow + tyw * 8 + 4];
            *(float4*)&b[0] = *(const float4*)&Bs[k][wcol + txw * 8];
            *(float4*)&b[4] = *(const float4*)&Bs[k][wcol + txw * 8 + 4];
            #pragma unroll
            for (int r = 0; r < 8; r++)
                #pragma unroll
                for (int c = 0; c < 8; c++)
                    acc[r][c] = fmaf(a[r], b[c], acc[r][c]);
        }
        __syncthreads();
    }

    // Epilogue: B = s_i*s_j - dot; dist = acosh(B); MAE over strict lower tri.
    const int ibase = rowbase + wrow + tyw * 8;
    const int jbase = colbase + wcol + txw * 8;
    float sr[8], sc[8];
    #pragma unroll
    for (int r = 0; r < 8; r++) sr[r] = s[ibase + r];
    #pragma unroll
    for (int c = 0; c < 8; c++) sc[c] = s[jbase + c];

    float lsum = 0.0f;
    #pragma unroll
    for (int r = 0; r < 8; r++) {
        const int i = ibase + r;
        const float* trow = tgt + (size_t)i * N + jbase;
        const float4 t0 = *(const float4*)(trow);
        const float4 t1 = *(const float4*)(trow + 4);
        float tv[8] = {t0.x, t0.y, t0.z, t0.w, t1.x, t1.y, t1.z, t1.w};
        #pragma unroll
        for (int c = 0; c < 8; c++) {
            const int j = jbase + c;
            if (j < i) {
                const float B = fmaf(sr[r], sc[c], -acc[r][c]);
                float dist;
                if (fabsf(B - 1.0f) < 1e-6f) {
                    dist = 0.0f;
                } else {
                    const float Bc = fmaxf(B, 1.0f);
                    dist = logf(Bc + sqrtf(fmaf(Bc, Bc, -1.0f)));
                }
                lsum += fabsf(dist - tv[c]);
            }
        }
    }

    // Reduce: wave shuffle -> LDS -> one atomic per block (pre-scaled).
    #pragma unroll
    for (int off = 32; off > 0; off >>= 1)
        lsum += __shfl_down(lsum, off, 64);
    if (lane == 0) wsum[wave] = lsum;
    __syncthreads();
    if (tid == 0) {
        const float tot = wsum[0] + wsum[1] + wsum[2] + wsum[3];
        atomicAdd(loss, tot * (1.0f / ((float)N * (float)(N - 1))));
    }
}

extern "C" void kernel_launch(void* const* d_in, const int* in_sizes, int n_in,
                              void* d_out, int out_size, void* d_ws, size_t ws_size,
                              hipStream_t stream) {
    const float* O   = (const float*)d_in[0];   // [4096,128] fp32
    const float* tgt = (const float*)d_in[1];   // [4096,4096] fp32
    float* loss = (float*)d_out;                // scalar
    float* s    = (float*)d_ws;                 // 4096 floats scratch

    snorm_kernel<<<N, 64, 0, stream>>>(O, s, loss);
    tile_loss_kernel<<<NBLK, 256, 0, stream>>>(O, s, tgt, loss);
}

// Round 2
// 142.614 us; speedup vs baseline: 1.0426x; 1.0426x over previous
//
#include <hip/hip_runtime.h>
#include <math.h>

#define N 4096
#define D 128
#define TS 64                      // output tile per wave
#define NT (N / TS)                // 64 tile rows
#define NBLK (NT * (NT + 1) / 2)   // 2080 lower-triangle tile pairs

typedef __attribute__((ext_vector_type(8))) short short8;  // 8 x bf16
typedef __attribute__((ext_vector_type(4))) float f32x4;

// Kernel 1: convert O to bf16 (RN) into ws, compute s[i] = sqrt(1+||o_i||^2),
// zero the loss accumulator. One wave per row, float2 per lane.
__global__ void prep_kernel(const float* __restrict__ O,
                            unsigned int* __restrict__ Obf_packed,
                            float* __restrict__ s,
                            float* __restrict__ loss) {
    const int row  = blockIdx.x;
    const int lane = threadIdx.x;                 // 0..63
    const float2 v = *(const float2*)(O + (size_t)row * D + 2 * lane);
    // round-to-nearest-even bf16
    const unsigned int ux = __float_as_uint(v.x);
    const unsigned int uy = __float_as_uint(v.y);
    const unsigned int bx = (ux + 0x7FFFu + ((ux >> 16) & 1u)) >> 16;
    const unsigned int by = (uy + 0x7FFFu + ((uy >> 16) & 1u)) >> 16;
    Obf_packed[row * (D / 2) + lane] = bx | (by << 16);   // little-endian: elt 2*lane low
    float acc = v.x * v.x + v.y * v.y;
    #pragma unroll
    for (int off = 32; off > 0; off >>= 1)
        acc += __shfl_down(acc, off, 64);
    if (lane == 0) {
        s[row] = sqrtf(1.0f + acc);
        if (row == 0) loss[0] = 0.0f;             // stream-ordered before kernel 2
    }
}

// Kernel 2: one wave per 64x64 lower-triangle tile. No LDS: A/B fragments are
// read straight from the L2-resident bf16 copy of O. 4x4 grid of 16x16x32
// bf16 MFMA fragments; fused acosh + masked-MAE epilogue; one atomic/wave.
__global__ __launch_bounds__(64, 2)
void tile_loss_kernel(const unsigned short* __restrict__ Obf,
                      const float* __restrict__ s,
                      const float* __restrict__ tgt,
                      float* __restrict__ loss) {
    // Linear tile id -> (ti, tj), tj <= ti
    const int t = blockIdx.x;
    int ti = (int)((sqrtf(8.0f * (float)t + 1.0f) - 1.0f) * 0.5f);
    while ((ti + 1) * (ti + 2) / 2 <= t) ti++;
    while (ti * (ti + 1) / 2 > t) ti--;
    const int tj = t - ti * (ti + 1) / 2;

    const int lane = threadIdx.x;                 // 0..63
    const int quad = lane >> 4;                   // 0..3
    const int l16  = lane & 15;

    const int ib = ti * TS;
    const int jb = tj * TS;

    f32x4 acc[4][4] = {};

    // K = 128, four 16x16x32 steps. A-frag: lane holds A[m=l16][k=quad*8+j].
    // B-frag (B^T row-major, i.e. rows of O): same layout with n=l16.
    #pragma unroll
    for (int kk = 0; kk < 4; kk++) {
        const int kof = kk * 32 + quad * 8;
        short8 a[4], b[4];
        #pragma unroll
        for (int m = 0; m < 4; m++)
            a[m] = *(const short8*)(Obf + (size_t)(ib + m * 16 + l16) * D + kof);
        #pragma unroll
        for (int n = 0; n < 4; n++)
            b[n] = *(const short8*)(Obf + (size_t)(jb + n * 16 + l16) * D + kof);
        #pragma unroll
        for (int m = 0; m < 4; m++)
            #pragma unroll
            for (int n = 0; n < 4; n++)
                acc[m][n] = __builtin_amdgcn_mfma_f32_16x16x32_bf16(
                    a[m], b[n], acc[m][n], 0, 0, 0);
    }

    // Epilogue. C/D layout (m89/m91): col = lane&15, row = quad*4 + reg.
    float sj[4];
    #pragma unroll
    for (int n = 0; n < 4; n++) sj[n] = s[jb + n * 16 + l16];

    float lsum = 0.0f;
    #pragma unroll
    for (int m = 0; m < 4; m++) {
        #pragma unroll
        for (int r = 0; r < 4; r++) {
            const int i = ib + m * 16 + quad * 4 + r;
            const float si = s[i];
            const float* trow = tgt + (size_t)i * N;
            #pragma unroll
            for (int n = 0; n < 4; n++) {
                const int j = jb + n * 16 + l16;
                if (j < i) {
                    const float B = fmaf(si, sj[n], -acc[m][n][r]);
                    float dist;
                    if (fabsf(B - 1.0f) < 1e-6f) {
                        dist = 0.0f;
                    } else {
                        const float Bc = fmaxf(B, 1.0f);
                        dist = logf(Bc + sqrtf(fmaf(Bc, Bc, -1.0f)));
                    }
                    lsum += fabsf(dist - trow[j]);
                }
            }
        }
    }

    #pragma unroll
    for (int off = 32; off > 0; off >>= 1)
        lsum += __shfl_down(lsum, off, 64);
    if (lane == 0)
        atomicAdd(loss, lsum * (1.0f / ((float)N * (float)(N - 1))));
}

extern "C" void kernel_launch(void* const* d_in, const int* in_sizes, int n_in,
                              void* d_out, int out_size, void* d_ws, size_t ws_size,
                              hipStream_t stream) {
    const float* O   = (const float*)d_in[0];   // [4096,128] fp32
    const float* tgt = (const float*)d_in[1];   // [4096,4096] fp32
    float* loss = (float*)d_out;                // scalar

    // ws layout: [0, 1MB) bf16 copy of O; [1MB, 1MB+16KB) s[]
    unsigned int* Obf_packed = (unsigned int*)d_ws;
    unsigned short* Obf      = (unsigned short*)d_ws;
    float* s = (float*)((char*)d_ws + (size_t)N * D * 2);

    prep_kernel<<<N, 64, 0, stream>>>(O, Obf_packed, s, loss);
    tile_loss_kernel<<<NBLK, 64, 0, stream>>>(Obf, s, tgt, loss);
}

// Round 3
// 122.739 us; speedup vs baseline: 1.2114x; 1.1619x over previous
//
#include <hip/hip_runtime.h>
#include <math.h>

#define N 4096
#define D 128
#define TS 64                      // output tile per 256-thread block
#define NT (N / TS)                // 64 tile rows
#define NBLK (NT * (NT + 1) / 2)   // 2080 lower-triangle tile pairs

typedef __attribute__((ext_vector_type(8))) short short8;  // 8 x bf16
typedef __attribute__((ext_vector_type(4))) float f32x4;

// Kernel 1: convert O to bf16 (RN) into ws, compute s[i] = sqrt(1+||o_i||^2),
// zero the loss accumulator. One wave per row, 4 rows per block.
__global__ __launch_bounds__(256)
void prep_kernel(const float* __restrict__ O,
                 unsigned int* __restrict__ Obf_packed,
                 float* __restrict__ s,
                 float* __restrict__ loss) {
    const int wave = threadIdx.x >> 6;
    const int lane = threadIdx.x & 63;
    const int row  = blockIdx.x * 4 + wave;
    const float2 v = *(const float2*)(O + (size_t)row * D + 2 * lane);
    // round-to-nearest-even bf16
    const unsigned int ux = __float_as_uint(v.x);
    const unsigned int uy = __float_as_uint(v.y);
    const unsigned int bx = (ux + 0x7FFFu + ((ux >> 16) & 1u)) >> 16;
    const unsigned int by = (uy + 0x7FFFu + ((uy >> 16) & 1u)) >> 16;
    Obf_packed[row * (D / 2) + lane] = bx | (by << 16);
    float acc = v.x * v.x + v.y * v.y;
    #pragma unroll
    for (int off = 32; off > 0; off >>= 1)
        acc += __shfl_down(acc, off, 64);
    if (lane == 0) {
        s[row] = sqrtf(1.0f + acc);
        if (row == 0 && wave == 0) loss[0] = 0.0f;  // stream-ordered before kernel 2
    }
}

__device__ __forceinline__ float acosh_dist(float B) {
    // clamp branch: |B-1| < 1e-6 -> 0 (inert for this data, B >= ~100)
    if (fabsf(B - 1.0f) < 1e-6f) return 0.0f;
    const float Bc = fmaxf(B, 1.0f);
    return logf(Bc + sqrtf(fmaf(Bc, Bc, -1.0f)));
}

// Kernel 2: one 256-thread block per 64x64 lower-triangle tile; each wave
// computes a 16x64 strip (1x4 row of 16x16x32 bf16 MFMA frags, K=128).
// No LDS for the GEMM (O-bf16 is 1 MB, L1/L2-resident). Fused acosh + MAE
// epilogue; LDS block reduction; one atomic per block.
__global__ __launch_bounds__(256, 4)
void tile_loss_kernel(const unsigned short* __restrict__ Obf,
                      const float* __restrict__ s,
                      const float* __restrict__ tgt,
                      float* __restrict__ loss) {
    __shared__ float wsum[4];

    // Linear tile id -> (ti, tj), tj <= ti
    const int t = blockIdx.x;
    int ti = (int)((sqrtf(8.0f * (float)t + 1.0f) - 1.0f) * 0.5f);
    while ((ti + 1) * (ti + 2) / 2 <= t) ti++;
    while (ti * (ti + 1) / 2 > t) ti--;
    const int tj = t - ti * (ti + 1) / 2;

    const int tid  = threadIdx.x;
    const int wave = tid >> 6;                    // 0..3 -> 16-row strip
    const int lane = tid & 63;
    const int quad = lane >> 4;                   // 0..3
    const int l16  = lane & 15;

    const int ib = ti * TS + wave * 16;           // this wave's 16 rows
    const int jb = tj * TS;

    f32x4 acc[4] = {};                            // 4 n-frags of 16x16

    // K = 128 in four 16x16x32 steps. A-frag: lane holds A[m=l16][k=quad*8+j].
    // B-frag: reg j holds B[k=quad*8+j][n=l16] = O[jb+n*16+l16][k] (B^T).
    #pragma unroll
    for (int kk = 0; kk < 4; kk++) {
        const int kof = kk * 32 + quad * 8;
        const short8 a = *(const short8*)(Obf + (size_t)(ib + l16) * D + kof);
        short8 b[4];
        #pragma unroll
        for (int n = 0; n < 4; n++)
            b[n] = *(const short8*)(Obf + (size_t)(jb + n * 16 + l16) * D + kof);
        #pragma unroll
        for (int n = 0; n < 4; n++)
            acc[n] = __builtin_amdgcn_mfma_f32_16x16x32_bf16(a, b[n], acc[n], 0, 0, 0);
    }

    // Epilogue. C/D layout: col = l16, row = quad*4 + reg (m89/m91).
    float sj[4];
    #pragma unroll
    for (int n = 0; n < 4; n++) sj[n] = s[jb + n * 16 + l16];

    const int i0 = ib + quad * 4;
    float si[4], tv[4][4];
    #pragma unroll
    for (int r = 0; r < 4; r++) {
        si[r] = s[i0 + r];
        const float* trow = tgt + (size_t)(i0 + r) * N + jb;
        #pragma unroll
        for (int n = 0; n < 4; n++)
            tv[r][n] = trow[n * 16 + l16];        // 16 independent loads -> MLP
    }

    float lsum = 0.0f;
    if (ti != tj) {
        // Off-diagonal tile: every (i,j) has j < i. No masking.
        #pragma unroll
        for (int r = 0; r < 4; r++)
            #pragma unroll
            for (int n = 0; n < 4; n++) {
                const float B = fmaf(si[r], sj[n], -acc[n][r]);
                lsum += fabsf(acosh_dist(B) - tv[r][n]);
            }
    } else {
        #pragma unroll
        for (int r = 0; r < 4; r++) {
            const int i = i0 + r;
            #pragma unroll
            for (int n = 0; n < 4; n++) {
                const int j = jb + n * 16 + l16;
                if (j < i) {
                    const float B = fmaf(si[r], sj[n], -acc[n][r]);
                    lsum += fabsf(acosh_dist(B) - tv[r][n]);
                }
            }
        }
    }

    // Reduce: wave shuffle -> LDS -> one atomic per block (pre-scaled).
    #pragma unroll
    for (int off = 32; off > 0; off >>= 1)
        lsum += __shfl_down(lsum, off, 64);
    if (lane == 0) wsum[wave] = lsum;
    __syncthreads();
    if (tid == 0) {
        const float tot = wsum[0] + wsum[1] + wsum[2] + wsum[3];
        atomicAdd(loss, tot * (1.0f / ((float)N * (float)(N - 1))));
    }
}

extern "C" void kernel_launch(void* const* d_in, const int* in_sizes, int n_in,
                              void* d_out, int out_size, void* d_ws, size_t ws_size,
                              hipStream_t stream) {
    const float* O   = (const float*)d_in[0];   // [4096,128] fp32
    const float* tgt = (const float*)d_in[1];   // [4096,4096] fp32
    float* loss = (float*)d_out;                // scalar

    // ws layout: [0, 1MB) bf16 copy of O; [1MB, 1MB+16KB) s[]
    unsigned int* Obf_packed = (unsigned int*)d_ws;
    unsigned short* Obf      = (unsigned short*)d_ws;
    float* s = (float*)((char*)d_ws + (size_t)N * D * 2);

    prep_kernel<<<N / 4, 256, 0, stream>>>(O, Obf_packed, s, loss);
    tile_loss_kernel<<<NBLK, 256, 0, stream>>>(Obf, s, tgt, loss);
}

// Round 4
// 115.419 us; speedup vs baseline: 1.2882x; 1.0634x over previous
//
#include <hip/hip_runtime.h>
#include <math.h>

#define N 4096
#define D 128
#define TS 64                      // output tile per 256-thread block
#define NT (N / TS)                // 64 tile rows
#define NBLK (NT * (NT + 1) / 2)   // 2080 lower-triangle tile pairs

typedef __attribute__((ext_vector_type(8))) short short8;  // 8 x bf16
typedef __attribute__((ext_vector_type(4))) float f32x4;

// Kernel 1: convert O to bf16 (RN) into ws, compute s[i] = sqrt(1+||o_i||^2).
// One wave per row, 4 rows per block.
__global__ __launch_bounds__(256)
void prep_kernel(const float* __restrict__ O,
                 unsigned int* __restrict__ Obf_packed,
                 float* __restrict__ s) {
    const int wave = threadIdx.x >> 6;
    const int lane = threadIdx.x & 63;
    const int row  = blockIdx.x * 4 + wave;
    const float2 v = *(const float2*)(O + (size_t)row * D + 2 * lane);
    // round-to-nearest-even bf16
    const unsigned int ux = __float_as_uint(v.x);
    const unsigned int uy = __float_as_uint(v.y);
    const unsigned int bx = (ux + 0x7FFFu + ((ux >> 16) & 1u)) >> 16;
    const unsigned int by = (uy + 0x7FFFu + ((uy >> 16) & 1u)) >> 16;
    Obf_packed[row * (D / 2) + lane] = bx | (by << 16);
    float acc = v.x * v.x + v.y * v.y;
    #pragma unroll
    for (int off = 32; off > 0; off >>= 1)
        acc += __shfl_down(acc, off, 64);
    if (lane == 0) s[row] = sqrtf(1.0f + acc);
}

__device__ __forceinline__ float acosh_dist(float B) {
    // clamp branch: |B-1| < 1e-6 -> 0 (inert for this data, B >= ~100)
    if (fabsf(B - 1.0f) < 1e-6f) return 0.0f;
    const float Bc = fmaxf(B, 1.0f);
    return logf(Bc + sqrtf(fmaf(Bc, Bc, -1.0f)));
}

// Kernel 2: one 256-thread block per 64x64 lower-triangle tile; each wave
// computes a 16x64 strip (1x4 row of 16x16x32 bf16 MFMA frags, K=128).
// No LDS for the GEMM (O-bf16 is 1 MB, L1/L2-resident). Fused acosh + MAE
// epilogue. NO same-address atomic: block partial -> partials[blockIdx].
__global__ __launch_bounds__(256, 4)
void tile_loss_kernel(const unsigned short* __restrict__ Obf,
                      const float* __restrict__ s,
                      const float* __restrict__ tgt,
                      float* __restrict__ partials) {
    __shared__ float wsum[4];

    // Linear tile id -> (ti, tj), tj <= ti
    const int t = blockIdx.x;
    int ti = (int)((sqrtf(8.0f * (float)t + 1.0f) - 1.0f) * 0.5f);
    while ((ti + 1) * (ti + 2) / 2 <= t) ti++;
    while (ti * (ti + 1) / 2 > t) ti--;
    const int tj = t - ti * (ti + 1) / 2;

    const int tid  = threadIdx.x;
    const int wave = tid >> 6;                    // 0..3 -> 16-row strip
    const int lane = tid & 63;
    const int quad = lane >> 4;                   // 0..3
    const int l16  = lane & 15;

    const int ib = ti * TS + wave * 16;           // this wave's 16 rows
    const int jb = tj * TS;

    f32x4 acc[4] = {};                            // 4 n-frags of 16x16

    // K = 128 in four 16x16x32 steps. A-frag: lane holds A[m=l16][k=quad*8+j].
    // B-frag: reg j holds B[k=quad*8+j][n=l16] = O[jb+n*16+l16][k] (B^T).
    #pragma unroll
    for (int kk = 0; kk < 4; kk++) {
        const int kof = kk * 32 + quad * 8;
        const short8 a = *(const short8*)(Obf + (size_t)(ib + l16) * D + kof);
        short8 b[4];
        #pragma unroll
        for (int n = 0; n < 4; n++)
            b[n] = *(const short8*)(Obf + (size_t)(jb + n * 16 + l16) * D + kof);
        #pragma unroll
        for (int n = 0; n < 4; n++)
            acc[n] = __builtin_amdgcn_mfma_f32_16x16x32_bf16(a, b[n], acc[n], 0, 0, 0);
    }

    // Epilogue. C/D layout: col = l16, row = quad*4 + reg (m89/m91).
    float sj[4];
    #pragma unroll
    for (int n = 0; n < 4; n++) sj[n] = s[jb + n * 16 + l16];

    const int i0 = ib + quad * 4;
    float si[4], tv[4][4];
    #pragma unroll
    for (int r = 0; r < 4; r++) {
        si[r] = s[i0 + r];
        const float* trow = tgt + (size_t)(i0 + r) * N + jb;
        #pragma unroll
        for (int n = 0; n < 4; n++)
            tv[r][n] = trow[n * 16 + l16];        // 16 independent loads -> MLP
    }

    float lsum = 0.0f;
    if (ti != tj) {
        // Off-diagonal tile: every (i,j) has j < i. No masking.
        #pragma unroll
        for (int r = 0; r < 4; r++)
            #pragma unroll
            for (int n = 0; n < 4; n++) {
                const float B = fmaf(si[r], sj[n], -acc[n][r]);
                lsum += fabsf(acosh_dist(B) - tv[r][n]);
            }
    } else {
        #pragma unroll
        for (int r = 0; r < 4; r++) {
            const int i = i0 + r;
            #pragma unroll
            for (int n = 0; n < 4; n++) {
                const int j = jb + n * 16 + l16;
                if (j < i) {
                    const float B = fmaf(si[r], sj[n], -acc[n][r]);
                    lsum += fabsf(acosh_dist(B) - tv[r][n]);
                }
            }
        }
    }

    // Reduce: wave shuffle -> LDS -> one plain store per block (no atomic).
    #pragma unroll
    for (int off = 32; off > 0; off >>= 1)
        lsum += __shfl_down(lsum, off, 64);
    if (lane == 0) wsum[wave] = lsum;
    __syncthreads();
    if (tid == 0)
        partials[t] = wsum[0] + wsum[1] + wsum[2] + wsum[3];
}

// Kernel 3: reduce the 2080 block partials, scale, write the scalar loss.
__global__ __launch_bounds__(256)
void final_reduce_kernel(const float* __restrict__ partials,
                         float* __restrict__ loss) {
    __shared__ float wsum[4];
    const int tid  = threadIdx.x;
    const int wave = tid >> 6;
    const int lane = tid & 63;
    float acc = 0.0f;
    for (int i = tid; i < NBLK; i += 256) acc += partials[i];
    #pragma unroll
    for (int off = 32; off > 0; off >>= 1)
        acc += __shfl_down(acc, off, 64);
    if (lane == 0) wsum[wave] = acc;
    __syncthreads();
    if (tid == 0) {
        const float tot = wsum[0] + wsum[1] + wsum[2] + wsum[3];
        loss[0] = tot * (1.0f / ((float)N * (float)(N - 1)));
    }
}

extern "C" void kernel_launch(void* const* d_in, const int* in_sizes, int n_in,
                              void* d_out, int out_size, void* d_ws, size_t ws_size,
                              hipStream_t stream) {
    const float* O   = (const float*)d_in[0];   // [4096,128] fp32
    const float* tgt = (const float*)d_in[1];   // [4096,4096] fp32
    float* loss = (float*)d_out;                // scalar

    // ws layout: [0,1MB) bf16 O; [1MB,+16KB) s[]; then partials[NBLK]
    unsigned int* Obf_packed = (unsigned int*)d_ws;
    unsigned short* Obf      = (unsigned short*)d_ws;
    float* s        = (float*)((char*)d_ws + (size_t)N * D * 2);
    float* partials = s + N;

    prep_kernel<<<N / 4, 256, 0, stream>>>(O, Obf_packed, s);
    tile_loss_kernel<<<NBLK, 256, 0, stream>>>(Obf, s, tgt, partials);
    final_reduce_kernel<<<1, 256, 0, stream>>>(partials, loss);
}

// Round 5
// 114.544 us; speedup vs baseline: 1.2981x; 1.0076x over previous
//
#include <hip/hip_runtime.h>
#include <math.h>

#define N 4096
#define D 128
#define TS 64                      // output tile per 256-thread block
#define NT (N / TS)                // 64 tile rows
#define NBLK (NT * (NT + 1) / 2)   // 2080 lower-triangle tile pairs
#define TPAD 68                    // tgt LDS row stride (floats): 16B-aligned, bank-rotating

typedef __attribute__((ext_vector_type(8))) short short8;  // 8 x bf16
typedef __attribute__((ext_vector_type(4))) float f32x4;

// Kernel 1: convert O to bf16 (RN) into ws, compute s[i] = sqrt(1+||o_i||^2).
__global__ __launch_bounds__(256)
void prep_kernel(const float* __restrict__ O,
                 unsigned int* __restrict__ Obf_packed,
                 float* __restrict__ s) {
    const int wave = threadIdx.x >> 6;
    const int lane = threadIdx.x & 63;
    const int row  = blockIdx.x * 4 + wave;
    const float2 v = *(const float2*)(O + (size_t)row * D + 2 * lane);
    const unsigned int ux = __float_as_uint(v.x);
    const unsigned int uy = __float_as_uint(v.y);
    const unsigned int bx = (ux + 0x7FFFu + ((ux >> 16) & 1u)) >> 16;
    const unsigned int by = (uy + 0x7FFFu + ((uy >> 16) & 1u)) >> 16;
    Obf_packed[row * (D / 2) + lane] = bx | (by << 16);
    float acc = v.x * v.x + v.y * v.y;
    #pragma unroll
    for (int off = 32; off > 0; off >>= 1)
        acc += __shfl_down(acc, off, 64);
    if (lane == 0) s[row] = sqrtf(1.0f + acc);
}

__device__ __forceinline__ float acosh_dist(float B) {
    // clamp branch |B-1|<1e-6 -> 0 (inert here: B >= ~100 for this data)
    if (fabsf(B - 1.0f) < 1e-6f) return 0.0f;
    const float Bc = fmaxf(B, 1.0f);
    // acosh(x) = ln(x + sqrt(x^2-1)) = log2(...) * ln2 ; v_log_f32 direct
    return __log2f(Bc + sqrtf(fmaf(Bc, Bc, -1.0f))) * 0.6931471805599453f;
}

// Kernel 2: one 256-thread block per 64x64 lower-triangle tile.
// Load structure: 3 drain episodes per wave:
//   (1) coalesced float4 staging of the tgt tile into padded LDS
//   (2,3) two batches of 10 frag loads (40 VGPRs) -> 8 MFMAs each
// Epilogue reads tv from LDS (2-way bank aliasing = free). One store/block.
__global__ __launch_bounds__(256, 4)
void tile_loss_kernel(const unsigned short* __restrict__ Obf,
                      const float* __restrict__ s,
                      const float* __restrict__ tgt,
                      float* __restrict__ partials) {
    __shared__ float T[TS][TPAD];   // 17.4 KB
    __shared__ float wsum[4];

    // Linear tile id -> (ti, tj), tj <= ti
    const int t = blockIdx.x;
    int ti = (int)((sqrtf(8.0f * (float)t + 1.0f) - 1.0f) * 0.5f);
    while ((ti + 1) * (ti + 2) / 2 <= t) ti++;
    while (ti * (ti + 1) / 2 > t) ti--;
    const int tj = t - ti * (ti + 1) / 2;

    const int tid  = threadIdx.x;
    const int wave = tid >> 6;                 // 0..3 -> 16-row strip
    const int lane = tid & 63;
    const int quad = lane >> 4;                // 0..3
    const int l16  = lane & 15;

    const int ib0 = ti * TS;                   // tile row base
    const int jb  = tj * TS;                   // tile col base
    const int ib  = ib0 + wave * 16;           // this wave's 16 rows

    // ---- Episode 1: stage tgt tile (64x64 f32) into LDS, fully coalesced.
    // 256 threads x 4 passes x float4 = 16 KB. Row segments are 256 B contig.
    {
        const int r = tid >> 4;                // 0..15 (row within pass group)
        const int c = (tid & 15) * 4;          // 0..60
        float4 tg[4];
        #pragma unroll
        for (int p = 0; p < 4; p++)
            tg[p] = *(const float4*)(tgt + (size_t)(ib0 + p * 16 + r) * N + jb + c);
        #pragma unroll
        for (int p = 0; p < 4; p++)
            *(float4*)&T[p * 16 + r][c] = tg[p];
    }

    // s-values: issue now so they drain with the frag batches.
    float sj[4];
    #pragma unroll
    for (int n = 0; n < 4; n++) sj[n] = s[jb + n * 16 + l16];
    const int r0 = wave * 16 + quad * 4;       // row within tile for C-frag regs
    float si[4];
    #pragma unroll
    for (int r = 0; r < 4; r++) si[r] = s[ib0 + r0 + r];

    // ---- Episodes 2,3: K=128 in two batches of (2 a-frags + 8 b-frags).
    f32x4 acc[4] = {};
    const unsigned short* arow = Obf + (size_t)(ib + l16) * D + quad * 8;
    #pragma unroll
    for (int kp = 0; kp < 2; kp++) {
        const int kof = kp * 64;
        const short8 a0 = *(const short8*)(arow + kof);
        const short8 a1 = *(const short8*)(arow + kof + 32);
        short8 b0[4], b1[4];
        #pragma unroll
        for (int n = 0; n < 4; n++) {
            const unsigned short* brow = Obf + (size_t)(jb + n * 16 + l16) * D + quad * 8;
            b0[n] = *(const short8*)(brow + kof);
            b1[n] = *(const short8*)(brow + kof + 32);
        }
        #pragma unroll
        for (int n = 0; n < 4; n++)
            acc[n] = __builtin_amdgcn_mfma_f32_16x16x32_bf16(a0, b0[n], acc[n], 0, 0, 0);
        #pragma unroll
        for (int n = 0; n < 4; n++)
            acc[n] = __builtin_amdgcn_mfma_f32_16x16x32_bf16(a1, b1[n], acc[n], 0, 0, 0);
    }

    __syncthreads();                            // tgt tile visible in LDS

    // ---- Epilogue. C/D layout: col = l16, row = quad*4 + reg (m89/m91).
    float lsum = 0.0f;
    if (ti != tj) {
        #pragma unroll
        for (int r = 0; r < 4; r++)
            #pragma unroll
            for (int n = 0; n < 4; n++) {
                const float B  = fmaf(si[r], sj[n], -acc[n][r]);
                const float tv = T[r0 + r][n * 16 + l16];
                lsum += fabsf(acosh_dist(B) - tv);
            }
    } else {
        #pragma unroll
        for (int r = 0; r < 4; r++) {
            const int i = ib0 + r0 + r;
            #pragma unroll
            for (int n = 0; n < 4; n++) {
                const int j = jb + n * 16 + l16;
                if (j < i) {
                    const float B  = fmaf(si[r], sj[n], -acc[n][r]);
                    const float tv = T[r0 + r][n * 16 + l16];
                    lsum += fabsf(acosh_dist(B) - tv);
                }
            }
        }
    }

    // Reduce: wave shuffle -> LDS -> one plain store per block.
    #pragma unroll
    for (int off = 32; off > 0; off >>= 1)
        lsum += __shfl_down(lsum, off, 64);
    if (lane == 0) wsum[wave] = lsum;
    __syncthreads();
    if (tid == 0)
        partials[t] = wsum[0] + wsum[1] + wsum[2] + wsum[3];
}

// Kernel 3: reduce the 2080 block partials, scale, write the scalar loss.
__global__ __launch_bounds__(256)
void final_reduce_kernel(const float* __restrict__ partials,
                         float* __restrict__ loss) {
    __shared__ float wsum[4];
    const int tid  = threadIdx.x;
    const int wave = tid >> 6;
    const int lane = tid & 63;
    float acc = 0.0f;
    for (int i = tid; i < NBLK; i += 256) acc += partials[i];
    #pragma unroll
    for (int off = 32; off > 0; off >>= 1)
        acc += __shfl_down(acc, off, 64);
    if (lane == 0) wsum[wave] = acc;
    __syncthreads();
    if (tid == 0) {
        const float tot = wsum[0] + wsum[1] + wsum[2] + wsum[3];
        loss[0] = tot * (1.0f / ((float)N * (float)(N - 1)));
    }
}

extern "C" void kernel_launch(void* const* d_in, const int* in_sizes, int n_in,
                              void* d_out, int out_size, void* d_ws, size_t ws_size,
                              hipStream_t stream) {
    const float* O   = (const float*)d_in[0];   // [4096,128] fp32
    const float* tgt = (const float*)d_in[1];   // [4096,4096] fp32
    float* loss = (float*)d_out;                // scalar

    // ws layout: [0,1MB) bf16 O; [1MB,+16KB) s[]; then partials[NBLK]
    unsigned int* Obf_packed = (unsigned int*)d_ws;
    unsigned short* Obf      = (unsigned short*)d_ws;
    float* s        = (float*)((char*)d_ws + (size_t)N * D * 2);
    float* partials = s + N;

    prep_kernel<<<N / 4, 256, 0, stream>>>(O, Obf_packed, s);
    tile_loss_kernel<<<NBLK, 256, 0, stream>>>(Obf, s, tgt, partials);
    final_reduce_kernel<<<1, 256, 0, stream>>>(partials, loss);
}

// Round 6
// 103.119 us; speedup vs baseline: 1.4419x; 1.1108x over previous
//
#include <hip/hip_runtime.h>
#include <math.h>

#define N 4096
#define D 128
#define TS 64                      // output tile per 256-thread block
#define NT (N / TS)                // 64 tile rows
#define NBLK (NT * (NT + 1) / 2)   // 2080 lower-triangle tile pairs
#define NG (N / 16)                // 256 row groups of 16
#define TPAD 68                    // tgt LDS row stride (floats)

typedef __attribute__((ext_vector_type(8))) short short8;  // 8 x bf16
typedef __attribute__((ext_vector_type(4))) float f32x4;

union frag_u { short8 v; unsigned int u[4]; };

__device__ __forceinline__ unsigned int pack_bf16x2(float a, float b) {
    unsigned int ua = __float_as_uint(a), ub = __float_as_uint(b);
    ua = (ua + 0x7FFFu + ((ua >> 16) & 1u)) >> 16;
    ub = (ub + 0x7FFFu + ((ub >> 16) & 1u)) >> 16;
    return ua | (ub << 16);
}

// Kernel 1: repack O into MFMA-fragment order + compute s[i]=sqrt(1+||o_i||^2).
// Ofrag[(g*4+kk)*64 + lane] = 8 bf16 of O[g*16+(lane&15)][kk*32+(lane>>4)*8 ..]
// -> every tile-kernel frag load is one lane-contiguous 1 KB burst.
__global__ __launch_bounds__(256)
void prep_kernel(const float* __restrict__ O,
                 short8* __restrict__ Ofrag,
                 float* __restrict__ s) {
    __shared__ float psum[16][17];
    const int g    = blockIdx.x;          // 16-row group
    const int tid  = threadIdx.x;
    const int kk   = tid >> 6;            // 0..3 (wave = K-chunk)
    const int lane = tid & 63;
    const int r16  = lane & 15;
    const int qd   = lane >> 4;           // 0..3
    const float* src = O + (size_t)(g * 16 + r16) * D + kk * 32 + qd * 8;
    const float4 v0 = *(const float4*)(src);
    const float4 v1 = *(const float4*)(src + 4);
    frag_u f;
    f.u[0] = pack_bf16x2(v0.x, v0.y);
    f.u[1] = pack_bf16x2(v0.z, v0.w);
    f.u[2] = pack_bf16x2(v1.x, v1.y);
    f.u[3] = pack_bf16x2(v1.z, v1.w);
    Ofrag[(g * 4 + kk) * 64 + lane] = f.v;
    // s: each thread holds 8 elements of row r16; reduce 16 partials per row.
    psum[kk * 4 + qd][r16] = v0.x * v0.x + v0.y * v0.y + v0.z * v0.z + v0.w * v0.w
                           + v1.x * v1.x + v1.y * v1.y + v1.z * v1.z + v1.w * v1.w;
    __syncthreads();
    if (tid < 16) {
        float acc = 1.0f;
        #pragma unroll
        for (int x = 0; x < 16; x++) acc += psum[x][tid];
        s[g * 16 + tid] = sqrtf(acc);
    }
}

__device__ __forceinline__ float acosh_dist(float B) {
    // clamp branch |B-1|<1e-6 -> 0 (inert here: B >= ~100 for this data)
    if (fabsf(B - 1.0f) < 1e-6f) return 0.0f;
    const float Bc = fmaxf(B, 1.0f);
    return __log2f(Bc + sqrtf(fmaf(Bc, Bc, -1.0f))) * 0.6931471805599453f;
}

// Kernel 2: one 256-thread block per 64x64 lower-triangle tile; each wave a
// 16x64 strip (1x4 frags, K=128 in 4 chunks). All frag loads are contiguous
// 1 KB bursts from the frag-ordered O copy. tgt staged coalesced into LDS.
__global__ __launch_bounds__(256, 4)
void tile_loss_kernel(const short8* __restrict__ Fr,
                      const float* __restrict__ s,
                      const float* __restrict__ tgt,
                      float* __restrict__ partials) {
    __shared__ float T[TS][TPAD];   // 17.4 KB
    __shared__ float wsum[4];

    const int t = blockIdx.x;
    int ti = (int)((sqrtf(8.0f * (float)t + 1.0f) - 1.0f) * 0.5f);
    while ((ti + 1) * (ti + 2) / 2 <= t) ti++;
    while (ti * (ti + 1) / 2 > t) ti--;
    const int tj = t - ti * (ti + 1) / 2;

    const int tid  = threadIdx.x;
    const int wave = tid >> 6;                 // 0..3 -> 16-row strip
    const int lane = tid & 63;
    const int quad = lane >> 4;
    const int l16  = lane & 15;

    const int ib0 = ti * TS;
    const int jb  = tj * TS;

    // ---- Stage tgt tile (64x64 f32) into LDS, fully coalesced.
    {
        const int r = tid >> 4;
        const int c = (tid & 15) * 4;
        float4 tg[4];
        #pragma unroll
        for (int p = 0; p < 4; p++)
            tg[p] = *(const float4*)(tgt + (size_t)(ib0 + p * 16 + r) * N + jb + c);
        #pragma unroll
        for (int p = 0; p < 4; p++)
            *(float4*)&T[p * 16 + r][c] = tg[p];
    }

    float sj[4];
    #pragma unroll
    for (int n = 0; n < 4; n++) sj[n] = s[jb + n * 16 + l16];
    const int r0 = wave * 16 + quad * 4;
    float si[4];
    #pragma unroll
    for (int r = 0; r < 4; r++) si[r] = s[ib0 + r0 + r];

    // ---- MFMA: K=128 as two batches of K-chunks {0,1} and {2,3}.
    // a-frag (g = ti*4+wave), b-frags (g = tj*4+n): 1 KB contiguous each.
    f32x4 acc[4] = {};
    const int ga4 = (ti * 4 + wave) * 4;
    const int gb4 = tj * 4 * 4;
    #pragma unroll
    for (int kp = 0; kp < 2; kp++) {
        const int k0 = kp * 2, k1 = kp * 2 + 1;
        const short8 a0 = Fr[(ga4 + k0) * 64 + lane];
        const short8 a1 = Fr[(ga4 + k1) * 64 + lane];
        short8 b0[4], b1[4];
        #pragma unroll
        for (int n = 0; n < 4; n++) {
            b0[n] = Fr[(gb4 + n * 4 + k0) * 64 + lane];
            b1[n] = Fr[(gb4 + n * 4 + k1) * 64 + lane];
        }
        #pragma unroll
        for (int n = 0; n < 4; n++)
            acc[n] = __builtin_amdgcn_mfma_f32_16x16x32_bf16(a0, b0[n], acc[n], 0, 0, 0);
        #pragma unroll
        for (int n = 0; n < 4; n++)
            acc[n] = __builtin_amdgcn_mfma_f32_16x16x32_bf16(a1, b1[n], acc[n], 0, 0, 0);
    }

    __syncthreads();                            // tgt tile visible in LDS

    // ---- Epilogue. C/D layout: col = l16, row = quad*4 + reg.
    float lsum = 0.0f;
    if (ti != tj) {
        #pragma unroll
        for (int r = 0; r < 4; r++)
            #pragma unroll
            for (int n = 0; n < 4; n++) {
                const float B  = fmaf(si[r], sj[n], -acc[n][r]);
                const float tv = T[r0 + r][n * 16 + l16];
                lsum += fabsf(acosh_dist(B) - tv);
            }
    } else {
        #pragma unroll
        for (int r = 0; r < 4; r++) {
            const int i = ib0 + r0 + r;
            #pragma unroll
            for (int n = 0; n < 4; n++) {
                const int j = jb + n * 16 + l16;
                if (j < i) {
                    const float B  = fmaf(si[r], sj[n], -acc[n][r]);
                    const float tv = T[r0 + r][n * 16 + l16];
                    lsum += fabsf(acosh_dist(B) - tv);
                }
            }
        }
    }

    #pragma unroll
    for (int off = 32; off > 0; off >>= 1)
        lsum += __shfl_down(lsum, off, 64);
    if (lane == 0) wsum[wave] = lsum;
    __syncthreads();
    if (tid == 0)
        partials[t] = wsum[0] + wsum[1] + wsum[2] + wsum[3];
}

// Kernel 3: reduce the 2080 block partials, scale, write the scalar loss.
__global__ __launch_bounds__(256)
void final_reduce_kernel(const float* __restrict__ partials,
                         float* __restrict__ loss) {
    __shared__ float wsum[4];
    const int tid  = threadIdx.x;
    const int wave = tid >> 6;
    const int lane = tid & 63;
    float acc = 0.0f;
    for (int i = tid; i < NBLK; i += 256) acc += partials[i];
    #pragma unroll
    for (int off = 32; off > 0; off >>= 1)
        acc += __shfl_down(acc, off, 64);
    if (lane == 0) wsum[wave] = acc;
    __syncthreads();
    if (tid == 0) {
        const float tot = wsum[0] + wsum[1] + wsum[2] + wsum[3];
        loss[0] = tot * (1.0f / ((float)N * (float)(N - 1)));
    }
}

extern "C" void kernel_launch(void* const* d_in, const int* in_sizes, int n_in,
                              void* d_out, int out_size, void* d_ws, size_t ws_size,
                              hipStream_t stream) {
    const float* O   = (const float*)d_in[0];   // [4096,128] fp32
    const float* tgt = (const float*)d_in[1];   // [4096,4096] fp32
    float* loss = (float*)d_out;                // scalar

    // ws layout: [0,1MB) frag-ordered bf16 O; [1MB,+16KB) s[]; then partials
    short8* Ofrag = (short8*)d_ws;
    float* s        = (float*)((char*)d_ws + (size_t)N * D * 2);
    float* partials = s + N;

    prep_kernel<<<NG, 256, 0, stream>>>(O, Ofrag, s);
    tile_loss_kernel<<<NBLK, 256, 0, stream>>>(Ofrag, s, tgt, partials);
    final_reduce_kernel<<<1, 256, 0, stream>>>(partials, loss);
}